// Round 10
// baseline (197.144 us; speedup 1.0000x reference)
//
#include <hip/hip_runtime.h>
#include <hip/hip_bf16.h>
#include <math.h>

#define N 2048
#define CIN 128
#define COUT 64
#define NEG 0.2f
#define NPANEL 32          // 64-row i-panels
#define NJBLK 32           // 64-row j-blocks
#define REP 32             // measurement multiplier (identical work per rep)

typedef __attribute__((ext_vector_type(8))) short short8;   // 8 bf16
typedef __attribute__((ext_vector_type(4))) float f32x4;

__device__ __forceinline__ short bf16bits(float x) {
  __hip_bfloat16 b = __float2bfloat16(x);
  return *reinterpret_cast<short*>(&b);
}

// opaque zero: defeats loop-invariant hoisting of the rep body
__device__ __forceinline__ int opaque_zero() {
  int z;
  asm volatile("s_mov_b32 %0, 0" : "=s"(z));
  return z;
}

// Kernel 1: h = data @ W; a_s = h@att_src; a_d = h@att_dst.
// h stored ONLY as bf16 in MFMA B-fragment order.
__global__ __launch_bounds__(64) void gat_gemm(
    const float* __restrict__ data, const float* __restrict__ W,
    const float* __restrict__ att_src, const float* __restrict__ att_dst,
    ushort* __restrict__ hfrag, float* __restrict__ a_s,
    float* __restrict__ a_d) {
  const int row = blockIdx.x;
  const int c = threadIdx.x;

  __shared__ float drow[CIN];
  drow[c]      = data[row * CIN + c];
  drow[c + 64] = data[row * CIN + 64 + c];
  __syncthreads();

  float a0 = 0.f, a1 = 0.f, a2 = 0.f, a3 = 0.f;
#pragma unroll
  for (int k = 0; k < CIN; k += 4) {
    a0 = fmaf(drow[k],     W[(k)     * COUT + c], a0);
    a1 = fmaf(drow[k + 1], W[(k + 1) * COUT + c], a1);
    a2 = fmaf(drow[k + 2], W[(k + 2) * COUT + c], a2);
    a3 = fmaf(drow[k + 3], W[(k + 3) * COUT + c], a3);
  }
  const float acc = (a0 + a1) + (a2 + a3);

  {
    const int p = row >> 6, ks = (row >> 5) & 1, r = row & 31;
    const int L = (r >> 3) * 16 + (c & 15);
    const int e = r & 7;
    const int f = (p * 2 + ks) * 4 + (c >> 4);
    hfrag[((size_t)(f * 64 + L) << 3) + e] = (ushort)bf16bits(acc);
  }

  float s = acc * att_src[c];
  float d = acc * att_dst[c];
#pragma unroll
  for (int o = 32; o; o >>= 1) {
    s += __shfl_xor(s, o);
    d += __shfl_xor(d, o);
  }
  if (c == 0) { a_s[row] = s; a_d[row] = d; }
}

// Kernel 2: MFMA attention tile (R8 structure, REP'd for attribution).
__global__ __launch_bounds__(256) void gat_attn_mfma(
    const ushort* __restrict__ hfrag, const float* __restrict__ a_s,
    const float* __restrict__ a_d, float* __restrict__ part,
    float* __restrict__ denp) {
  const int bj = (int)blockIdx.x;       // j-block 0..31
  const int p  = (int)blockIdx.y;       // i-panel 0..31
  if (p > bj) return;
  const bool diag = (p == bj);

  const int tid = (int)threadIdx.x;
  const int wid = tid >> 6;
  const int lane = tid & 63;
  const int j0w = bj * 64 + wid * 16;
  const int jme = j0w + (lane & 15);
  const int kgrp = lane >> 4;
  const float ad_me = a_d[jme];

#pragma unroll 1
  for (int rep = 0; rep < REP; ++rep) {
    const int z = opaque_zero();                 // re-execute body each rep
    const float* az = a_s + z;
    const uint4* hf = (const uint4*)hfrag + z;
    float* pz = part + z;
    float* dz = denp + z;

    f32x4 acc0 = {0.f, 0.f, 0.f, 0.f};
    f32x4 acc1 = acc0, acc2 = acc0, acc3 = acc0;
    float dsum = 0.f;

#pragma unroll
    for (int ks = 0; ks < 2; ++ks) {
      const int ibase = p * 64 + ks * 32 + kgrp * 8;
      const float4 asa = *(const float4*)&az[ibase];
      const float4 asb = *(const float4*)&az[ibase + 4];
      const float av[8] = {asa.x, asa.y, asa.z, asa.w,
                           asb.x, asb.y, asb.z, asb.w};
      short8 af;
#pragma unroll
      for (int e = 0; e < 8; ++e) {
        float x = av[e] + ad_me;
        x = fmaxf(x, NEG * x);
        float w = __expf(x);
        if (diag && (ibase + e > jme)) w = 0.f;
        dsum += w;
        af[e] = bf16bits(w);
      }
      const int fbase = ((p * 2 + ks) * 4) * 64 + lane;
      const uint4 b0 = hf[fbase];
      const uint4 b1 = hf[fbase + 64];
      const uint4 b2 = hf[fbase + 128];
      const uint4 b3 = hf[fbase + 192];
      acc0 = __builtin_amdgcn_mfma_f32_16x16x32_bf16(af, *(const short8*)&b0,
                                                     acc0, 0, 0, 0);
      acc1 = __builtin_amdgcn_mfma_f32_16x16x32_bf16(af, *(const short8*)&b1,
                                                     acc1, 0, 0, 0);
      acc2 = __builtin_amdgcn_mfma_f32_16x16x32_bf16(af, *(const short8*)&b2,
                                                     acc2, 0, 0, 0);
      acc3 = __builtin_amdgcn_mfma_f32_16x16x32_bf16(af, *(const short8*)&b3,
                                                     acc3, 0, 0, 0);
    }

    dsum += __shfl_xor(dsum, 16);
    dsum += __shfl_xor(dsum, 32);
    if (lane < 16) dz[p * N + j0w + lane] = dsum;

    float* pb = pz + (size_t)p * (N * COUT) + (size_t)j0w * COUT;
#pragma unroll
    for (int r = 0; r < 4; ++r) {
      const int jr = (kgrp * 4 + r) * COUT + (lane & 15);
      pb[jr]      = acc0[r];
      pb[jr + 16] = acc1[r];
      pb[jr + 32] = acc2[r];
      pb[jr + 48] = acc3[r];
    }
  }
}

// Kernel 3: out = relu(sum_p part / sum_p denp + bias). REP'd.
__global__ __launch_bounds__(256) void gat_final(
    const float* __restrict__ part, const float* __restrict__ denp,
    const float* __restrict__ bias, float* __restrict__ out) {
  const int idx = blockIdx.x * 256 + threadIdx.x;
  const int j = idx >> 6;
  const int c = idx & 63;
  const int ns = (j >> 6) + 1;

#pragma unroll 1
  for (int rep = 0; rep < REP; ++rep) {
    const int z = opaque_zero();
    const float* pz = part + z;
    const float* dz = denp + z;
    float num = 0.f, den = 0.f;
    for (int s = 0; s < ns; ++s) {
      num += pz[(size_t)s * (N * COUT) + idx];
      den += dz[s * N + j];
    }
    const float v = num / den + bias[c];
    out[idx] = v > 0.f ? v : 0.f;
  }
}

extern "C" void kernel_launch(void* const* d_in, const int* in_sizes, int n_in,
                              void* d_out, int out_size, void* d_ws, size_t ws_size,
                              hipStream_t stream) {
  const float* data    = (const float*)d_in[0];  // [N, CIN]
  const float* W       = (const float*)d_in[1];  // [CIN, COUT]
  const float* att_src = (const float*)d_in[2];  // [COUT]
  const float* att_dst = (const float*)d_in[3];  // [COUT]
  const float* bias    = (const float*)d_in[4];  // [COUT]
  float* out = (float*)d_out;                    // [N, COUT]

  ushort* hfrag = (ushort*)d_ws;                 // N*COUT bf16 (256KB)
  float* a_s  = (float*)d_ws + 65536;            // N
  float* a_d  = a_s + N;                         // N
  float* part = a_d + N;                         // NPANEL*N*COUT (16MB)
  float* denp = part + (size_t)NPANEL * N * COUT;// NPANEL*N

  gat_gemm<<<N, 64, 0, stream>>>(data, W, att_src, att_dst, hfrag, a_s, a_d);
  gat_attn_mfma<<<dim3(NJBLK, NPANEL), 256, 0, stream>>>(hfrag, a_s, a_d,
                                                         part, denp);
  gat_final<<<(N * COUT) / 256, 256, 0, stream>>>(part, denp, bias, out);
}

// Round 11
// 18.799 us; speedup vs baseline: 10.4868x; 10.4868x over previous
//
#include <hip/hip_runtime.h>
#include <hip/hip_bf16.h>
#include <math.h>

#define N 2048
#define CIN 128
#define COUT 64
#define NEG 0.2f
#define JB 16              // j-rows per attn block
#define NJB (N / JB)       // 128 attn blocks

typedef __attribute__((ext_vector_type(8))) short short8;   // 8 bf16
typedef __attribute__((ext_vector_type(4))) float f32x4;

__device__ __forceinline__ short bf16bits(float x) {
  __hip_bfloat16 b = __float2bfloat16(x);
  return *reinterpret_cast<short*>(&b);
}

// Kernel 1: h = data @ W; a_s = h@att_src; a_d = h@att_dst.
// 4 rows per block (one wave each). h stored ONLY as bf16 in MFMA
// B-fragment order: frame f = (i>>5)*4 + (c>>4),
// lane L = ((i>>3)&3)*16 + (c&15), elem e = i&7.
__global__ __launch_bounds__(256) void gat_gemm(
    const float* __restrict__ data, const float* __restrict__ W,
    const float* __restrict__ att_src, const float* __restrict__ att_dst,
    ushort* __restrict__ hfrag, float* __restrict__ a_s,
    float* __restrict__ a_d) {
  const int wid = threadIdx.x >> 6;
  const int c = threadIdx.x & 63;
  const int row = blockIdx.x * 4 + wid;

  __shared__ float drow[4][CIN];
  float* dr = drow[wid];
  dr[c]      = data[row * CIN + c];
  dr[c + 64] = data[row * CIN + 64 + c];
  __syncthreads();   // cheap; guarantees LDS visibility

  float a0 = 0.f, a1 = 0.f, a2 = 0.f, a3 = 0.f;
#pragma unroll
  for (int k = 0; k < CIN; k += 4) {
    a0 = fmaf(dr[k],     W[(k)     * COUT + c], a0);
    a1 = fmaf(dr[k + 1], W[(k + 1) * COUT + c], a1);
    a2 = fmaf(dr[k + 2], W[(k + 2) * COUT + c], a2);
    a3 = fmaf(dr[k + 3], W[(k + 3) * COUT + c], a3);
  }
  const float acc = (a0 + a1) + (a2 + a3);

  {
    const int L = ((row >> 3) & 3) * 16 + (c & 15);
    const int e = row & 7;
    const int f = (row >> 5) * 4 + (c >> 4);
    hfrag[((size_t)(f * 64 + L) << 3) + e] = (ushort)bf16bits(acc);
  }

  float s = acc * att_src[c];
  float d = acc * att_dst[c];
#pragma unroll
  for (int o = 32; o; o >>= 1) {
    s += __shfl_xor(s, o);
    d += __shfl_xor(d, o);
  }
  if (c == 0) { a_s[row] = s; a_d[row] = d; }
}

// Kernel 2: flash-style triangular MFMA attention. Block bj owns 16 j's;
// 4 waves split the K=32 i-steps round-robin; in-register softmax weights;
// one LDS cross-wave reduce; epilogue divides by den, adds bias, relu,
// writes out. No partials, no atomics, no fences.
__global__ __launch_bounds__(256) void gat_attn_flash(
    const ushort* __restrict__ hfrag, const float* __restrict__ a_s,
    const float* __restrict__ a_d, const float* __restrict__ bias,
    float* __restrict__ out) {
  const int bj = NJB - 1 - (int)blockIdx.x;   // heavy blocks first
  const int tid = (int)threadIdx.x;
  const int wid = tid >> 6;
  const int lane = tid & 63;
  const int j0 = bj * JB;
  const int jme = j0 + (lane & 15);           // this lane's A-frag j-row
  const int kgrp = lane >> 4;                 // k-chunk 0..3
  const float ad_me = a_d[jme];
  const int nks = (bj + 2) >> 1;              // ceil((bj+1)/2) K=32 steps

  f32x4 acc0 = {0.f, 0.f, 0.f, 0.f};
  f32x4 acc1 = acc0, acc2 = acc0, acc3 = acc0;
  float dsum = 0.f;
  const uint4* hf = (const uint4*)hfrag;

  for (int ks = wid; ks < nks; ks += 4) {
    const int ibase = ks * 32 + kgrp * 8;
    const float4 asa = *(const float4*)&a_s[ibase];
    const float4 asb = *(const float4*)&a_s[ibase + 4];
    const float av[8] = {asa.x, asa.y, asa.z, asa.w,
                         asb.x, asb.y, asb.z, asb.w};
    short8 af;
#pragma unroll
    for (int e = 0; e < 8; ++e) {
      float x = av[e] + ad_me;
      x = fmaxf(x, NEG * x);                  // leaky_relu
      float w = __expf(x);                    // no max-shift (logits bounded)
      if (ibase + e > jme) w = 0.f;           // causal mask i <= j
      dsum += w;
      af[e] = bf16bits(w);
    }
    const int fbase = (ks * 4) * 64 + lane;
    const uint4 b0 = hf[fbase];
    const uint4 b1 = hf[fbase + 64];
    const uint4 b2 = hf[fbase + 128];
    const uint4 b3 = hf[fbase + 192];
    acc0 = __builtin_amdgcn_mfma_f32_16x16x32_bf16(af, *(const short8*)&b0,
                                                   acc0, 0, 0, 0);
    acc1 = __builtin_amdgcn_mfma_f32_16x16x32_bf16(af, *(const short8*)&b1,
                                                   acc1, 0, 0, 0);
    acc2 = __builtin_amdgcn_mfma_f32_16x16x32_bf16(af, *(const short8*)&b2,
                                                   acc2, 0, 0, 0);
    acc3 = __builtin_amdgcn_mfma_f32_16x16x32_bf16(af, *(const short8*)&b3,
                                                   acc3, 0, 0, 0);
  }

  // den: reduce over the 4 k-chunks within the wave (all lanes get den[j])
  dsum += __shfl_xor(dsum, 16);
  dsum += __shfl_xor(dsum, 32);

  // cross-wave reduce via LDS: rbuf[r16][wid][lane] (lane-contiguous, no
  // bank conflicts); dbuf holds per-wave den partials.
  __shared__ float rbuf[16][4][64];
  __shared__ float dbuf[4][16];
#pragma unroll
  for (int r = 0; r < 4; ++r) {
    rbuf[0 * 4 + r][wid][lane]  = acc0[r];
    rbuf[1 * 4 + r][wid][lane]  = acc1[r];
    rbuf[2 * 4 + r][wid][lane]  = acc2[r];
    rbuf[3 * 4 + r][wid][lane]  = acc3[r];
  }
  if (lane < 16) dbuf[wid][lane] = dsum;
  __syncthreads();

#pragma unroll
  for (int q = 0; q < 4; ++q) {
    const int r16 = wid * 4 + q;   // 0..15: (c-tile t = r16>>2, reg r = r16&3)
    const float v = rbuf[r16][0][lane] + rbuf[r16][1][lane] +
                    rbuf[r16][2][lane] + rbuf[r16][3][lane];
    const int j = (lane >> 4) * 4 + (r16 & 3);       // C/D row
    const int c = (r16 >> 2) * 16 + (lane & 15);     // C/D col
    const float den = dbuf[0][j] + dbuf[1][j] + dbuf[2][j] + dbuf[3][j];
    const float o = v / den + bias[c];
    out[(size_t)(j0 + j) * COUT + c] = o > 0.f ? o : 0.f;
  }
}

extern "C" void kernel_launch(void* const* d_in, const int* in_sizes, int n_in,
                              void* d_out, int out_size, void* d_ws, size_t ws_size,
                              hipStream_t stream) {
  const float* data    = (const float*)d_in[0];  // [N, CIN]
  const float* W       = (const float*)d_in[1];  // [CIN, COUT]
  const float* att_src = (const float*)d_in[2];  // [COUT]
  const float* att_dst = (const float*)d_in[3];  // [COUT]
  const float* bias    = (const float*)d_in[4];  // [COUT]
  float* out = (float*)d_out;                    // [N, COUT]

  ushort* hfrag = (ushort*)d_ws;                 // N*COUT bf16 (256KB)
  float* a_s  = (float*)d_ws + 65536;            // N
  float* a_d  = a_s + N;                         // N

  gat_gemm<<<N / 4, 256, 0, stream>>>(data, W, att_src, att_dst, hfrag,
                                      a_s, a_d);
  gat_attn_flash<<<NJB, 256, 0, stream>>>(hfrag, a_s, a_d, bias, out);
}

// Round 12
// 15.418 us; speedup vs baseline: 12.7863x; 1.2193x over previous
//
#include <hip/hip_runtime.h>
#include <hip/hip_bf16.h>
#include <math.h>

#define N 2048
#define CIN 128
#define COUT 64
#define NEG 0.2f
#define JB 16              // j-rows per attn block
#define NJB (N / JB)       // 128 attn blocks

typedef __attribute__((ext_vector_type(8))) short short8;   // 8 bf16
typedef __attribute__((ext_vector_type(4))) float f32x4;

__device__ __forceinline__ ushort bf16u(float x) {
  __hip_bfloat16 b = __float2bfloat16(x);
  return *reinterpret_cast<ushort*>(&b);
}
__device__ __forceinline__ uint pack2(float lo, float hi) {
  return (uint)bf16u(lo) | ((uint)bf16u(hi) << 16);
}

// Kernel 1: MFMA gemm. 32 blocks x 1024 threads; block = 64-row i-tile.
// h = data@W via mfma_f32_16x16x32_bf16 (A = data rows, B = W cols).
// Outputs: hfrag (bf16, attention-B-frag order — layout verified on-device
// in R8/R11), a_s, a_d (fp32, via in-register column reductions).
__global__ __launch_bounds__(1024) void gat_gemm_mfma(
    const float* __restrict__ data, const float* __restrict__ W,
    const float* __restrict__ att_src, const float* __restrict__ att_dst,
    ushort* __restrict__ hfrag, float* __restrict__ a_s,
    float* __restrict__ a_d) {
  const int tid = (int)threadIdx.x;
  const int i0 = (int)blockIdx.x * 64;

  __shared__ ushort abuf[16 * 64 * 8];  // A-frags [mi][kc][lane][8] (16KB)
  __shared__ ushort wbuf[16 * 64 * 8];  // B-frags [kc][cf][lane][8] (16KB)
  __shared__ float asp[4 * 64];         // a_s partials [ci][i_loc]
  __shared__ float adp[4 * 64];         // a_d partials [ci][i_loc]

  // ---- stage data tile (64x128 fp32 -> bf16 A-frags) ----
  // thread tid = (mi<<8)|(kc<<6)|L handles one 8-elem frag slot.
  {
    const int mi = tid >> 8, kc = (tid >> 6) & 3, L = tid & 63;
    const int row = i0 + mi * 16 + (L & 15);
    const int col = kc * 32 + (L >> 4) * 8;
    const float4 f0 = *(const float4*)&data[row * CIN + col];
    const float4 f1 = *(const float4*)&data[row * CIN + col + 4];
    uint4 pa;
    pa.x = pack2(f0.x, f0.y);
    pa.y = pack2(f0.z, f0.w);
    pa.z = pack2(f1.x, f1.y);
    pa.w = pack2(f1.z, f1.w);
    *(uint4*)&abuf[tid * 8] = pa;   // ((mi*4+kc)*64+L)*8 == tid*8
  }
  // ---- stage W (128x64 fp32 -> bf16 B-frags) ----
  {
    const int kc = tid >> 8, cf = (tid >> 6) & 3, L = tid & 63;
    const int krow = kc * 32 + (L >> 4) * 8;
    const int c = cf * 16 + (L & 15);
    ushort uw[8];
#pragma unroll
    for (int e = 0; e < 8; ++e) uw[e] = bf16u(W[(krow + e) * COUT + c]);
    uint4 pw;
    pw.x = (uint)uw[0] | ((uint)uw[1] << 16);
    pw.y = (uint)uw[2] | ((uint)uw[3] << 16);
    pw.z = (uint)uw[4] | ((uint)uw[5] << 16);
    pw.w = (uint)uw[6] | ((uint)uw[7] << 16);
    *(uint4*)&wbuf[tid * 8] = pw;   // ((kc*4+cf)*64+L)*8 == tid*8
  }
  __syncthreads();

  // ---- MFMA: wave w computes C-tile (mi = w>>2, ci = w&3), K=128 ----
  const int w = tid >> 6, lane = tid & 63;
  const int mi = w >> 2, ci = w & 3;
  f32x4 acc = {0.f, 0.f, 0.f, 0.f};
#pragma unroll
  for (int kc = 0; kc < 4; ++kc) {
    const short8 a = *(const short8*)&abuf[((mi * 4 + kc) * 64 + lane) * 8];
    const short8 b = *(const short8*)&wbuf[((kc * 4 + ci) * 64 + lane) * 8];
    acc = __builtin_amdgcn_mfma_f32_16x16x32_bf16(a, b, acc, 0, 0, 0);
  }

  // ---- epilogue: hfrag store + a_s/a_d reductions ----
  // C/D: col = ci*16 + (lane&15), rows = mi*16 + (lane>>4)*4 + r.
  const int q = lane >> 4;
  const int colg = ci * 16 + (lane & 15);
  const float sc = att_src[colg];
  const float dc = att_dst[colg];
  float ps[4], pd[4];
#pragma unroll
  for (int r = 0; r < 4; ++r) { ps[r] = acc[r] * sc; pd[r] = acc[r] * dc; }
#pragma unroll
  for (int off = 1; off < 16; off <<= 1) {
#pragma unroll
    for (int r = 0; r < 4; ++r) {
      ps[r] += __shfl_xor(ps[r], off);
      pd[r] += __shfl_xor(pd[r], off);
    }
  }
  if ((lane & 15) == 0) {
#pragma unroll
    for (int r = 0; r < 4; ++r) {
      asp[ci * 64 + mi * 16 + q * 4 + r] = ps[r];
      adp[ci * 64 + mi * 16 + q * 4 + r] = pd[r];
    }
  }
  // hfrag: frame f = (i>>5)*4 + ci, lane' = ((i>>3)&3)*16 + (c&15), e = i&7;
  // the lane's 4 rows land in 4 consecutive elems -> one 8B store.
  {
    const int ib = i0 + mi * 16 + q * 4;
    const int f = (ib >> 5) * 4 + ci;
    const int lp = ((ib >> 3) & 3) * 16 + (lane & 15);
    uint2 hv;
    hv.x = pack2(acc[0], acc[1]);
    hv.y = pack2(acc[2], acc[3]);
    *(uint2*)&hfrag[((size_t)(f * 64 + lp) << 3) + (ib & 7)] = hv;
  }
  __syncthreads();
  if (tid < 64) {
    a_s[i0 + tid] = asp[tid] + asp[64 + tid] + asp[128 + tid] + asp[192 + tid];
    a_d[i0 + tid] = adp[tid] + adp[64 + tid] + adp[128 + tid] + adp[192 + tid];
  }
}

// Kernel 2: flash triangular MFMA attention. 128 blocks x 1024 threads;
// block bj owns 16 j's; 16 waves split K=32 i-steps round-robin (heavy
// block: 4 steps/wave). In-register softmax weights, 16-wave LDS reduce,
// fused den-divide + bias + relu epilogue.
__global__ __launch_bounds__(1024) void gat_attn_flash(
    const ushort* __restrict__ hfrag, const float* __restrict__ a_s,
    const float* __restrict__ a_d, const float* __restrict__ bias,
    float* __restrict__ out) {
  const int bj = NJB - 1 - (int)blockIdx.x;   // heavy blocks first
  const int tid = (int)threadIdx.x;
  const int wid = tid >> 6;                   // 0..15
  const int lane = tid & 63;
  const int j0 = bj * JB;
  const int jme = j0 + (lane & 15);
  const int kgrp = lane >> 4;
  const float ad_me = a_d[jme];
  const int nks = (bj + 2) >> 1;              // K=32 steps covering i<=j0+15

  f32x4 acc0 = {0.f, 0.f, 0.f, 0.f};
  f32x4 acc1 = acc0, acc2 = acc0, acc3 = acc0;
  float dsum = 0.f;
  const uint4* hf = (const uint4*)hfrag;

  for (int ks = wid; ks < nks; ks += 16) {
    const int ibase = ks * 32 + kgrp * 8;
    const float4 asa = *(const float4*)&a_s[ibase];
    const float4 asb = *(const float4*)&a_s[ibase + 4];
    const float av[8] = {asa.x, asa.y, asa.z, asa.w,
                         asb.x, asb.y, asb.z, asb.w};
    short8 af;
#pragma unroll
    for (int e = 0; e < 8; ++e) {
      float x = av[e] + ad_me;
      x = fmaxf(x, NEG * x);                  // leaky_relu
      float wgt = __expf(x);                  // no max-shift (logits bounded)
      if (ibase + e > jme) wgt = 0.f;         // causal mask i <= j
      dsum += wgt;
      af[e] = (short)bf16u(wgt);
    }
    const int fbase = (ks * 4) * 64 + lane;
    const uint4 b0 = hf[fbase];
    const uint4 b1 = hf[fbase + 64];
    const uint4 b2 = hf[fbase + 128];
    const uint4 b3 = hf[fbase + 192];
    acc0 = __builtin_amdgcn_mfma_f32_16x16x32_bf16(af, *(const short8*)&b0,
                                                   acc0, 0, 0, 0);
    acc1 = __builtin_amdgcn_mfma_f32_16x16x32_bf16(af, *(const short8*)&b1,
                                                   acc1, 0, 0, 0);
    acc2 = __builtin_amdgcn_mfma_f32_16x16x32_bf16(af, *(const short8*)&b2,
                                                   acc2, 0, 0, 0);
    acc3 = __builtin_amdgcn_mfma_f32_16x16x32_bf16(af, *(const short8*)&b3,
                                                   acc3, 0, 0, 0);
  }

  // den over the 4 k-chunks within the wave
  dsum += __shfl_xor(dsum, 16);
  dsum += __shfl_xor(dsum, 32);

  __shared__ float rbuf[16][16][64];   // [t16*4+r][wid][lane] (64KB)
  __shared__ float dbuf[16][16];       // [wid][j]
#pragma unroll
  for (int r = 0; r < 4; ++r) {
    rbuf[0 + r][wid][lane]  = acc0[r];
    rbuf[4 + r][wid][lane]  = acc1[r];
    rbuf[8 + r][wid][lane]  = acc2[r];
    rbuf[12 + r][wid][lane] = acc3[r];
  }
  if (lane < 16) dbuf[wid][lane] = dsum;
  __syncthreads();

  // epilogue: thread e handles output elem (j = e>>6, c = e&63)
  {
    const int j = tid >> 6, c = tid & 63;
    const int qq = j >> 2, rr = j & 3, t16 = c >> 4, n = c & 15;
    float num = 0.f, den = 0.f;
#pragma unroll
    for (int ww = 0; ww < 16; ++ww) {
      num += rbuf[t16 * 4 + rr][ww][qq * 16 + n];
      den += dbuf[ww][j];
    }
    const float v = num / den + bias[c];
    out[(size_t)(j0 + j) * COUT + c] = v > 0.f ? v : 0.f;
  }
}

extern "C" void kernel_launch(void* const* d_in, const int* in_sizes, int n_in,
                              void* d_out, int out_size, void* d_ws, size_t ws_size,
                              hipStream_t stream) {
  const float* data    = (const float*)d_in[0];  // [N, CIN]
  const float* W       = (const float*)d_in[1];  // [CIN, COUT]
  const float* att_src = (const float*)d_in[2];  // [COUT]
  const float* att_dst = (const float*)d_in[3];  // [COUT]
  const float* bias    = (const float*)d_in[4];  // [COUT]
  float* out = (float*)d_out;                    // [N, COUT]

  ushort* hfrag = (ushort*)d_ws;                 // N*COUT bf16 (256KB)
  float* a_s  = (float*)d_ws + 65536;            // N
  float* a_d  = a_s + N;                         // N

  gat_gemm_mfma<<<N / 64, 1024, 0, stream>>>(data, W, att_src, att_dst,
                                             hfrag, a_s, a_d);
  gat_attn_flash<<<NJB, 1024, 0, stream>>>(hfrag, a_s, a_d, bias, out);
}

// Round 13
// 15.112 us; speedup vs baseline: 13.0453x; 1.0203x over previous
//
#include <hip/hip_runtime.h>
#include <hip/hip_bf16.h>
#include <math.h>

#define N 2048
#define CIN 128
#define COUT 64
#define NEG 0.2f
#define JB 16              // j-rows per attn block
#define NJB (N / JB)       // 128 attn blocks

typedef __attribute__((ext_vector_type(8))) short short8;   // 8 bf16
typedef __attribute__((ext_vector_type(4))) float f32x4;

__device__ __forceinline__ ushort bf16u(float x) {
  __hip_bfloat16 b = __float2bfloat16(x);
  return *reinterpret_cast<ushort*>(&b);
}
__device__ __forceinline__ uint pack2(float lo, float hi) {
  return (uint)bf16u(lo) | ((uint)bf16u(hi) << 16);
}

// Kernel 1: slim MFMA gemm. 128 blocks x 256 threads; block = 16-row tile.
// All 4 waves share the tile's A-frags -> load/pack A global->reg (no LDS,
// no barrier on the MFMA path). Wave ci owns output cols [ci*16, ci*16+16).
// Epilogue: hfrag store (verified B-frag order) + a_s/a_d via 16-lane
// shuffle tree + tiny LDS cross-wave sum.
__global__ __launch_bounds__(256) void gat_gemm_mfma(
    const float* __restrict__ data, const float* __restrict__ W,
    const float* __restrict__ att_src, const float* __restrict__ att_dst,
    ushort* __restrict__ hfrag, float* __restrict__ a_s,
    float* __restrict__ a_d) {
  const int tid = (int)threadIdx.x;
  const int ci = tid >> 6;            // wave = output col-tile
  const int lane = tid & 63;
  const int i0 = (int)blockIdx.x * 16;
  const int q = lane >> 4;            // k-subgroup / C-row group
  const int n15 = lane & 15;
  const int mrow = i0 + n15;          // A-frag row for this lane

  // A-frags: af[kc][e] = bf16(data[mrow][kc*32 + q*8 + e])
  short8 af[4];
#pragma unroll
  for (int kc = 0; kc < 4; ++kc) {
    const int col = kc * 32 + q * 8;
    const float4 f0 = *(const float4*)&data[mrow * CIN + col];
    const float4 f1 = *(const float4*)&data[mrow * CIN + col + 4];
    uint4 pa;
    pa.x = pack2(f0.x, f0.y);
    pa.y = pack2(f0.z, f0.w);
    pa.z = pack2(f1.x, f1.y);
    pa.w = pack2(f1.z, f1.w);
    af[kc] = *(short8*)&pa;
  }

  // B-frags + MFMA: bf[kc][e] = bf16(W[kc*32 + q*8 + e][ci*16 + n15])
  const int cg = ci * 16 + n15;
  f32x4 acc = {0.f, 0.f, 0.f, 0.f};
#pragma unroll
  for (int kc = 0; kc < 4; ++kc) {
    const int kr = kc * 32 + q * 8;
    ushort uw[8];
#pragma unroll
    for (int e = 0; e < 8; ++e) uw[e] = bf16u(W[(kr + e) * COUT + cg]);
    uint4 pw;
    pw.x = (uint)uw[0] | ((uint)uw[1] << 16);
    pw.y = (uint)uw[2] | ((uint)uw[3] << 16);
    pw.z = (uint)uw[4] | ((uint)uw[5] << 16);
    pw.w = (uint)uw[6] | ((uint)uw[7] << 16);
    acc = __builtin_amdgcn_mfma_f32_16x16x32_bf16(af[kc], *(short8*)&pw,
                                                  acc, 0, 0, 0);
  }

  // hfrag store: C/D row ib+r (ib = i0+q*4), col cg. Frag coords:
  // frame f=(ib>>5)*4+ci, lane' lp, elem e0; 4 consecutive elems -> 8B store.
  {
    const int ib = i0 + q * 4;
    const int f = (ib >> 5) * 4 + ci;
    const int lp = ((ib >> 3) & 3) * 16 + n15;
    uint2 hv;
    hv.x = pack2(acc[0], acc[1]);
    hv.y = pack2(acc[2], acc[3]);
    *(uint2*)&hfrag[((size_t)(f * 64 + lp) << 3) + (ib & 7)] = hv;
  }

  // a_s/a_d: per-wave partial over its 16 cols, then cross-wave LDS sum
  __shared__ float asp[4][16];
  __shared__ float adp[4][16];
  {
    const float sc = att_src[cg];
    const float dc = att_dst[cg];
    float ps[4], pd[4];
#pragma unroll
    for (int r = 0; r < 4; ++r) { ps[r] = acc[r] * sc; pd[r] = acc[r] * dc; }
#pragma unroll
    for (int off = 1; off < 16; off <<= 1) {
#pragma unroll
      for (int r = 0; r < 4; ++r) {
        ps[r] += __shfl_xor(ps[r], off);
        pd[r] += __shfl_xor(pd[r], off);
      }
    }
    if (n15 == 0) {
#pragma unroll
      for (int r = 0; r < 4; ++r) {
        asp[ci][q * 4 + r] = ps[r];
        adp[ci][q * 4 + r] = pd[r];
      }
    }
  }
  __syncthreads();
  if (tid < 16) {
    a_s[i0 + tid] = asp[0][tid] + asp[1][tid] + asp[2][tid] + asp[3][tid];
    a_d[i0 + tid] = adp[0][tid] + adp[1][tid] + adp[2][tid] + adp[3][tid];
  }
}

// Kernel 2: flash triangular MFMA attention (unchanged from R12).
__global__ __launch_bounds__(1024) void gat_attn_flash(
    const ushort* __restrict__ hfrag, const float* __restrict__ a_s,
    const float* __restrict__ a_d, const float* __restrict__ bias,
    float* __restrict__ out) {
  const int bj = NJB - 1 - (int)blockIdx.x;   // heavy blocks first
  const int tid = (int)threadIdx.x;
  const int wid = tid >> 6;                   // 0..15
  const int lane = tid & 63;
  const int j0 = bj * JB;
  const int jme = j0 + (lane & 15);
  const int kgrp = lane >> 4;
  const float ad_me = a_d[jme];
  const int nks = (bj + 2) >> 1;              // K=32 steps covering i<=j0+15

  f32x4 acc0 = {0.f, 0.f, 0.f, 0.f};
  f32x4 acc1 = acc0, acc2 = acc0, acc3 = acc0;
  float dsum = 0.f;
  const uint4* hf = (const uint4*)hfrag;

  for (int ks = wid; ks < nks; ks += 16) {
    const int ibase = ks * 32 + kgrp * 8;
    const float4 asa = *(const float4*)&a_s[ibase];
    const float4 asb = *(const float4*)&a_s[ibase + 4];
    const float av[8] = {asa.x, asa.y, asa.z, asa.w,
                         asb.x, asb.y, asb.z, asb.w};
    short8 af;
#pragma unroll
    for (int e = 0; e < 8; ++e) {
      float x = av[e] + ad_me;
      x = fmaxf(x, NEG * x);                  // leaky_relu
      float wgt = __expf(x);                  // no max-shift (logits bounded)
      if (ibase + e > jme) wgt = 0.f;         // causal mask i <= j
      dsum += wgt;
      af[e] = (short)bf16u(wgt);
    }
    const int fbase = (ks * 4) * 64 + lane;
    const uint4 b0 = hf[fbase];
    const uint4 b1 = hf[fbase + 64];
    const uint4 b2 = hf[fbase + 128];
    const uint4 b3 = hf[fbase + 192];
    acc0 = __builtin_amdgcn_mfma_f32_16x16x32_bf16(af, *(const short8*)&b0,
                                                   acc0, 0, 0, 0);
    acc1 = __builtin_amdgcn_mfma_f32_16x16x32_bf16(af, *(const short8*)&b1,
                                                   acc1, 0, 0, 0);
    acc2 = __builtin_amdgcn_mfma_f32_16x16x32_bf16(af, *(const short8*)&b2,
                                                   acc2, 0, 0, 0);
    acc3 = __builtin_amdgcn_mfma_f32_16x16x32_bf16(af, *(const short8*)&b3,
                                                   acc3, 0, 0, 0);
  }

  // den over the 4 k-chunks within the wave
  dsum += __shfl_xor(dsum, 16);
  dsum += __shfl_xor(dsum, 32);

  __shared__ float rbuf[16][16][64];   // [t16*4+r][wid][lane] (64KB)
  __shared__ float dbuf[16][16];       // [wid][j]
#pragma unroll
  for (int r = 0; r < 4; ++r) {
    rbuf[0 + r][wid][lane]  = acc0[r];
    rbuf[4 + r][wid][lane]  = acc1[r];
    rbuf[8 + r][wid][lane]  = acc2[r];
    rbuf[12 + r][wid][lane] = acc3[r];
  }
  if (lane < 16) dbuf[wid][lane] = dsum;
  __syncthreads();

  // epilogue: thread handles output elem (j = tid>>6, c = tid&63)
  {
    const int j = tid >> 6, c = tid & 63;
    const int qq = j >> 2, rr = j & 3, t16 = c >> 4, n = c & 15;
    float num = 0.f, den = 0.f;
#pragma unroll
    for (int ww = 0; ww < 16; ++ww) {
      num += rbuf[t16 * 4 + rr][ww][qq * 16 + n];
      den += dbuf[ww][j];
    }
    const float v = num / den + bias[c];
    out[(size_t)(j0 + j) * COUT + c] = v > 0.f ? v : 0.f;
  }
}

extern "C" void kernel_launch(void* const* d_in, const int* in_sizes, int n_in,
                              void* d_out, int out_size, void* d_ws, size_t ws_size,
                              hipStream_t stream) {
  const float* data    = (const float*)d_in[0];  // [N, CIN]
  const float* W       = (const float*)d_in[1];  // [CIN, COUT]
  const float* att_src = (const float*)d_in[2];  // [COUT]
  const float* att_dst = (const float*)d_in[3];  // [COUT]
  const float* bias    = (const float*)d_in[4];  // [COUT]
  float* out = (float*)d_out;                    // [N, COUT]

  ushort* hfrag = (ushort*)d_ws;                 // N*COUT bf16 (256KB)
  float* a_s  = (float*)d_ws + 65536;            // N
  float* a_d  = a_s + N;                         // N

  gat_gemm_mfma<<<N / 16, 256, 0, stream>>>(data, W, att_src, att_dst,
                                            hfrag, a_s, a_d);
  gat_attn_flash<<<NJB, 1024, 0, stream>>>(hfrag, a_s, a_d, bias, out);
}